// Round 11
// baseline (2010.552 us; speedup 1.0000x reference)
//
#include <hip/hip_runtime.h>
#include <cstdint>
#include <cstddef>

namespace {
constexpr int kP0 = 31;
constexpr int kM0 = 496;   // 16 n-seqs * 31 pairs at step 0
}

// ---------------- device state ----------------
__device__ float g_state[2][64 * 32 * 256];     // ping-pong per-b state
__device__ float g_nh[2][64 * kP0 * 256];       // pair-row cell outputs
__device__ float g_s5[2][64 * kP0 * 5];
__device__ float g_nh0[kM0 * 256];              // step-0 n-indexed
__device__ float g_s50[kM0 * 5];
__device__ float g_inter0[(size_t)kM0 * 1024];
__device__ float g_cont0[(size_t)kM0 * 1024];
__device__ float g_accu[64];
__device__ int g_slots[2][128];

// ---------------- threefry2x32 (bit-exact jax, verified passing) ----------------
__device__ __forceinline__ void tf2x32(uint32_t k0, uint32_t k1, uint32_t x0,
                                       uint32_t x1, uint32_t& o0, uint32_t& o1) {
  uint32_t ks2 = k0 ^ k1 ^ 0x1BD11BDAu;
  x0 += k0; x1 += k1;
#define TF_ROT(v, r) (((v) << (r)) | ((v) >> (32 - (r))))
#define TF_RD(r) { x0 += x1; x1 = TF_ROT(x1, r); x1 ^= x0; }
  TF_RD(13) TF_RD(15) TF_RD(26) TF_RD(6)   x0 += k1;  x1 += ks2 + 1u;
  TF_RD(17) TF_RD(29) TF_RD(16) TF_RD(24)  x0 += ks2; x1 += k0 + 2u;
  TF_RD(13) TF_RD(15) TF_RD(26) TF_RD(6)   x0 += k0;  x1 += k1 + 3u;
  TF_RD(17) TF_RD(29) TF_RD(16) TF_RD(24)  x0 += k1;  x1 += ks2 + 4u;
  TF_RD(13) TF_RD(15) TF_RD(26) TF_RD(6)   x0 += ks2; x1 += k0 + 5u;
  o0 = x0; o1 = x1;
#undef TF_RD
#undef TF_ROT
}

__device__ __forceinline__ float blockSum256(float v, float* red4, int tid) {
#pragma unroll
  for (int o = 32; o > 0; o >>= 1) v += __shfl_down(v, o, 64);
  __syncthreads();
  if ((tid & 63) == 0) red4[tid >> 6] = v;
  __syncthreads();
  return red4[0] + red4[1] + red4[2] + red4[3];
}
// 1024-thread variant: only waves 0..3 are meaningful; identical arithmetic.
__device__ __forceinline__ float bs16(float v, float* red16, int tid) {
#pragma unroll
  for (int o = 32; o > 0; o >>= 1) v += __shfl_down(v, o, 64);
  __syncthreads();
  if ((tid & 63) == 0) red16[tid >> 6] = v;
  __syncthreads();
  return red16[0] + red16[1] + red16[2] + red16[3];
}
__device__ __forceinline__ float waveMax64(float v) {
#pragma unroll
  for (int o = 32; o > 0; o >>= 1) v = fmaxf(v, __shfl_xor(v, o, 64));
  return v;
}
__device__ __forceinline__ float waveSum64(float v) {
#pragma unroll
  for (int o = 32; o > 0; o >>= 1) v += __shfl_xor(v, o, 64);
  return v;
}
__device__ __forceinline__ float geluf(float v) {
  return 0.5f * v * (1.0f + erff(v * 0.70710678118654752440f));
}

// ---------------- embed + LN, replicate to B copies ----------------
__global__ __launch_bounds__(256) void k_embed(const float* __restrict__ x,
                                               const float* __restrict__ wW,
                                               const float* __restrict__ wb,
                                               const float* __restrict__ lng,
                                               const float* __restrict__ lnb) {
  int row = blockIdx.x;
  int d = threadIdx.x;
  __shared__ float xs[256];
  __shared__ float red4[4];
  xs[d] = x[row * 256 + d];
  __syncthreads();
  float acc = wb[d];
  for (int k = 0; k < 256; ++k) acc = fmaf(xs[k], wW[k * 256 + d], acc);
  float mean = blockSum256(acc, red4, d) * (1.0f / 256.0f);
  float cen = acc - mean;
  float var = blockSum256(cen * cen, red4, d) * (1.0f / 256.0f);
  float o = cen / sqrtf(var + 1e-5f) * lng[d] + lnb[d];
  int n = row >> 5, s = row & 31;
#pragma unroll
  for (int bb = 0; bb < 4; ++bb)
    g_state[0][((n * 4 + bb) * 32 + s) * 256 + d] = o;
  if (row == 0 && d < 64) g_accu[d] = 0.0f;
}

// =============== step-0 GEMMs (128 thr, 4x4/thread, measured 45us) ===============

__global__ __launch_bounds__(128) void k_g1s(const float* __restrict__ w1,
                                             const float* __restrict__ b1) {
  __shared__ float As[64][20];
  __shared__ float Ws[64][132];
  const int tid = threadIdx.x;
  const int colB = blockIdx.x * 128;
  const int rowB = blockIdx.y * 16;
  const int rg = tid >> 5, cgp = tid & 31;
  const int ar = tid & 15, kq = tid >> 4;
  const int wc = tid & 31, wk = tid >> 5;
  const float* Ab;
  {
    int m = rowB + ar;
    int n = m / 31, j = m - n * 31;
    Ab = g_state[0] + (n * 4) * 8192 + j * 256;
  }
  float acc[4][4] = {};
  for (int c = 0; c < 8; ++c) {
    const int kb = c * 64;
#pragma unroll
    for (int q = 0; q < 2; ++q) {
      int kp = kq * 8 + q * 4;
      float4 a = *(const float4*)&Ab[kb + kp];
      As[kp + 0][ar] = a.x; As[kp + 1][ar] = a.y;
      As[kp + 2][ar] = a.z; As[kp + 3][ar] = a.w;
    }
#pragma unroll
    for (int q = 0; q < 16; ++q) {
      int kk = wk * 16 + q;
      *(float4*)&Ws[kk][wc * 4] =
          *(const float4*)&w1[(size_t)(kb + kk) * 1024 + colB + wc * 4];
    }
    __syncthreads();
#pragma unroll
    for (int kk = 0; kk < 64; ++kk) {
      float4 a4 = *(const float4*)&As[kk][rg * 4];
      float4 w4 = *(const float4*)&Ws[kk][cgp * 4];
      float av[4] = {a4.x, a4.y, a4.z, a4.w};
      float wv[4] = {w4.x, w4.y, w4.z, w4.w};
#pragma unroll
      for (int ri = 0; ri < 4; ++ri)
#pragma unroll
        for (int ci = 0; ci < 4; ++ci)
          acc[ri][ci] = fmaf(av[ri], wv[ci], acc[ri][ci]);
    }
    __syncthreads();
  }
  const int col = colB + cgp * 4;
  float4 bb = *(const float4*)&b1[col];
#pragma unroll
  for (int ri = 0; ri < 4; ++ri) {
    int m = rowB + rg * 4 + ri;
    float4 o;
    o.x = geluf(acc[ri][0] + bb.x); o.y = geluf(acc[ri][1] + bb.y);
    o.z = geluf(acc[ri][2] + bb.z); o.w = geluf(acc[ri][3] + bb.w);
    *(float4*)&g_inter0[(size_t)m * 1024 + col] = o;
  }
}

__global__ __launch_bounds__(128) void k_g2s(const float* __restrict__ w2) {
  __shared__ float As[64][20];
  __shared__ float Ws[64][132];
  const int tid = threadIdx.x;
  const int colB = blockIdx.x * 128;
  const int rowB = blockIdx.y * 16;
  const int rg = tid >> 5, cgp = tid & 31;
  const int ar = tid & 15, kq = tid >> 4;
  const int wc = tid & 31, wk = tid >> 5;
  const float* Ab = g_inter0 + (size_t)(rowB + ar) * 1024;
  float acc[4][4] = {};
  for (int c = 0; c < 16; ++c) {
    const int kb = c * 64;
#pragma unroll
    for (int q = 0; q < 2; ++q) {
      int kp = kq * 8 + q * 4;
      float4 a = *(const float4*)&Ab[kb + kp];
      As[kp + 0][ar] = a.x; As[kp + 1][ar] = a.y;
      As[kp + 2][ar] = a.z; As[kp + 3][ar] = a.w;
    }
#pragma unroll
    for (int q = 0; q < 16; ++q) {
      int kk = wk * 16 + q;
      *(float4*)&Ws[kk][wc * 4] =
          *(const float4*)&w2[(size_t)(kb + kk) * 1024 + colB + wc * 4];
    }
    __syncthreads();
#pragma unroll
    for (int kk = 0; kk < 64; ++kk) {
      float4 a4 = *(const float4*)&As[kk][rg * 4];
      float4 w4 = *(const float4*)&Ws[kk][cgp * 4];
      float av[4] = {a4.x, a4.y, a4.z, a4.w};
      float wv[4] = {w4.x, w4.y, w4.z, w4.w};
#pragma unroll
      for (int ri = 0; ri < 4; ++ri)
#pragma unroll
        for (int ci = 0; ci < 4; ++ci)
          acc[ri][ci] = fmaf(av[ri], wv[ci], acc[ri][ci]);
    }
    __syncthreads();
  }
  const int col = colB + cgp * 4;
#pragma unroll
  for (int ri = 0; ri < 4; ++ri) {
    int m = rowB + rg * 4 + ri;
    float4 o = {acc[ri][0], acc[ri][1], acc[ri][2], acc[ri][3]};
    *(float4*)&g_cont0[(size_t)m * 1024 + col] = o;
  }
}

// ---------------- step-0 cell (all 496 rows) ----------------
__global__ __launch_bounds__(256) void k_cellfull(const float* __restrict__ imask,
                                                  const float* __restrict__ ln2g,
                                                  const float* __restrict__ ln2b,
                                                  const float* __restrict__ decW,
                                                  const float* __restrict__ b2) {
  int m = blockIdx.x;
  int d = threadIdx.x;
  int n = m / 31, j = m - n * 31;
  const float* st = g_state[0] + (n * 4) * 8192;
  const float* crow = g_cont0 + (size_t)m * 1024;
  float c0 = crow[d] + b2[d];
  float c1 = crow[256 + d] + b2[256 + d];
  float c2 = crow[512 + d] + b2[512 + d];
  float c3 = crow[768 + d] + b2[768 + d];
  float l = st[j * 256 + d];
  float r = st[(j + 1) * 256 + d];
  float f1 = 1.0f / (1.0f + expf(-c0));
  float f2 = 1.0f / (1.0f + expf(-c1));
  float ig = 1.0f / (1.0f + expf(-c2));
  float pre = f1 * l + f2 * r + ig * c3;
  __shared__ float red4[4];
  __shared__ float w5[4][5];
  float mean = blockSum256(pre, red4, d) * (1.0f / 256.0f);
  float cen = pre - mean;
  float var = blockSum256(cen * cen, red4, d) * (1.0f / 256.0f);
  float nh = cen / sqrtf(var + 1e-5f) * ln2g[d] + ln2b[d];
  g_nh0[m * 256 + d] = nh;
  float mv = imask[n * 32 + 1 + j];
  float nhm = nh * mv;
  float pv[5];
#pragma unroll
  for (int t = 0; t < 5; ++t) pv[t] = nhm * decW[t * 256 + d];
#pragma unroll
  for (int t = 0; t < 5; ++t)
#pragma unroll
    for (int o = 32; o > 0; o >>= 1) pv[t] += __shfl_down(pv[t], o, 64);
  __syncthreads();
  if ((d & 63) == 0) {
#pragma unroll
    for (int t = 0; t < 5; ++t) w5[d >> 6][t] = pv[t];
  }
  __syncthreads();
  if (d < 5) g_s50[m * 5 + d] = w5[0][d] + w5[1][d] + w5[2][d] + w5[3][d];
}

// ---------------- step-0 decide + merge (grid (64,8), 256 thr) ----------------
__global__ __launch_bounds__(256) void k_cm0(
    const float* __restrict__ imask, const float* __restrict__ decW,
    const float* __restrict__ decb, const float* __restrict__ ln2g,
    const float* __restrict__ ln2b) {
  const int b = blockIdx.x, grp = blockIdx.y;
  const int tid = threadIdx.x, lane = tid & 63, wv = tid >> 6;
  const int Sc = 31;
  const int n32 = (b >> 2) * 32;
  __shared__ int sh_k;
  __shared__ float sh_sv;
  const float* s5Src = g_s50 + (b >> 2) * kP0 * 5;
  const float* nhSrcG = g_nh0 + (size_t)(b >> 2) * kP0 * 256;
  const float* stOld = g_state[0] + b * 8192;
  float* stNew = g_state[1] + b * 8192;
  float* nhDst = g_nh[1] + (size_t)b * kP0 * 256;
  float* s5Dst = g_s5[1] + b * kP0 * 5;
  float done = imask[n32 + 1];

  if (tid < 64) {
    int j = lane;
    bool act = j < Sc;
    float mv = 0.f, lg = 0.f;
    if (act) {
      mv = imask[n32 + 1 + j];
      float t5 = decb[0];
      if (j >= 2) t5 += s5Src[(j - 2) * 5 + 0];
      if (j >= 1) t5 += s5Src[(j - 1) * 5 + 1];
      t5 += s5Src[j * 5 + 2];
      if (j + 1 < Sc) t5 += s5Src[(j + 1) * 5 + 3];
      if (j + 2 < Sc) t5 += s5Src[(j + 2) * 5 + 4];
      lg = t5 / 35.77708763999664f;
    }
    uint32_t fk0, fk1, o0, o1;
    tf2x32(0u, 1234u, 0u, 0u, fk0, fk1);
    uint32_t idx = (uint32_t)(b * Sc + j);
    tf2x32(fk0, fk1, 0u, idx, o0, o1);
    uint32_t bits = o0 ^ o1;
    float u = __uint_as_float((bits >> 9) | 0x3f800000u) - 1.0f;
    float gum = -logf(-logf(u + 1e-20f) + 1e-20f);
    float z = lg + gum;
    float zm = waveMax64(act ? z : -3.0e38f);
    float e = act ? expf(z - zm) : 0.f;
    float p = e / waveSum64(e);
    float y = act ? (p * mv + 1e-20f) : 0.f;
    float ys = y / waveSum64(y);
    float av = act ? ys : -1.f;
    int ai = j;
#pragma unroll
    for (int o = 32; o > 0; o >>= 1) {
      float ov = __shfl_xor(av, o, 64);
      int oi = __shfl_xor(ai, o, 64);
      if (ov > av || (ov == av && oi < ai)) { av = ov; ai = oi; }
    }
    float lm = waveMax64(act ? lg : -3.0e38f);
    float e2 = act ? expf(lg - lm) : 0.f;
    float p2 = e2 / waveSum64(e2);
    float y2 = act ? (p2 * mv + 1e-20f) : 0.f;
    float ps = y2 / waveSum64(y2);
    float ysk = __shfl(ys, ai, 64);
    float psk = __shfl(ps, ai, 64);
    float sv = (1.0f - ysk) + ysk;
    if (j == 0) {
      sh_k = ai;
      sh_sv = sv;
      if (grp == 0) {
        g_accu[b] += done * logf(sv * psk + 1e-20f);
        int s0 = -1, s1 = -1;
        if (done != 0.0f) {
          if (ai >= 1) s0 = ai - 1;
          if (ai <= Sc - 2) s1 = ai;
        }
        g_slots[1][2 * b] = s0;
        g_slots[1][2 * b + 1] = s1;
      }
    }
  }
  __syncthreads();

  int k = sh_k;
  float sv = sh_sv;
  {
    int jrow = grp * 4 + wv;
    if (jrow < Sc) {
      float4 ol = *(const float4*)&stOld[jrow * 256 + lane * 4];
      float4 ov4;
      if (done != 0.0f) {
        float4 mg;
        if (jrow < k) {
          mg = ol;
        } else if (jrow == k) {
          float4 nh4 = *(const float4*)&nhSrcG[k * 256 + lane * 4];
          mg.x = sv * nh4.x + (1.0f - sv) * ol.x;
          mg.y = sv * nh4.y + (1.0f - sv) * ol.y;
          mg.z = sv * nh4.z + (1.0f - sv) * ol.z;
          mg.w = sv * nh4.w + (1.0f - sv) * ol.w;
        } else {
          float4 orr = *(const float4*)&stOld[(jrow + 1) * 256 + lane * 4];
          mg.x = (1.0f - sv) * ol.x + sv * orr.x;
          mg.y = (1.0f - sv) * ol.y + sv * orr.y;
          mg.z = (1.0f - sv) * ol.z + sv * orr.z;
          mg.w = (1.0f - sv) * ol.w + sv * orr.w;
        }
        ov4.x = done * mg.x + (1.0f - done) * ol.x;
        ov4.y = done * mg.y + (1.0f - done) * ol.y;
        ov4.z = done * mg.z + (1.0f - done) * ol.z;
        ov4.w = done * mg.w + (1.0f - done) * ol.w;
      } else {
        ov4 = ol;
      }
      *(float4*)&stNew[jrow * 256 + lane * 4] = ov4;
      if (jrow < Sc - 1) {
        int src = (done != 0.0f && jrow > k) ? jrow + 1 : jrow;
        float4 nv = *(const float4*)&nhSrcG[src * 256 + lane * 4];
        *(float4*)&nhDst[jrow * 256 + lane * 4] = nv;
        float mv2 = imask[n32 + 2 + jrow];
        float pv[5];
#pragma unroll
        for (int t = 0; t < 5; ++t) {
          const float* dw = decW + t * 256 + lane * 4;
          pv[t] = (nv.x * dw[0] + nv.y * dw[1] + nv.z * dw[2] + nv.w * dw[3]) * mv2;
        }
#pragma unroll
        for (int t = 0; t < 5; ++t) {
          float v = pv[t];
#pragma unroll
          for (int o = 32; o > 0; o >>= 1) v += __shfl_down(v, o, 64);
          pv[t] = v;
        }
        if (lane == 0) {
#pragma unroll
          for (int t = 0; t < 5; ++t) s5Dst[jrow * 5 + t] = pv[t];
        }
      }
    }
  }
}

// ---------------- persistent tail: steps 1..30, one block per b ----------------
__global__ __launch_bounds__(1024, 1) void k_tail(
    const float* __restrict__ imask, const float* __restrict__ decW,
    const float* __restrict__ decb, const float* __restrict__ b1,
    const float* __restrict__ b2, const float* __restrict__ ln2g,
    const float* __restrict__ ln2b, const float* __restrict__ w1,
    const float* __restrict__ w2) {
  const int b = blockIdx.x;
  const int tid = threadIdx.x;
  const int lane = tid & 63, wv = tid >> 6;
  const int n32 = (b >> 2) * 32;
  __shared__ float S[4][2][1024];     // split-K partials (32KB)
  __shared__ float IC[2][1024];       // inter, then cont (8KB)
  __shared__ float As2[2][512];       // staged A row-pairs (4KB)
  __shared__ float sh_nhf[2][256];
  __shared__ float sh_s5f[2][5];
  __shared__ float s5buf[2][32][5];   // s5 ping-pong
  __shared__ float red16[16];
  __shared__ float w5s[4][5];
  __shared__ int sh_slot0, sh_slot1;
  __shared__ int sh_k;
  __shared__ float sh_sv;
  __shared__ float sh_accu;

  if (tid < 150) s5buf[1][tid / 5][tid % 5] = g_s5[1][b * kP0 * 5 + tid];
  if (tid == 0) {
    sh_slot0 = g_slots[1][2 * b];
    sh_slot1 = g_slots[1][2 * b + 1];
    sh_accu = g_accu[b];
  }
  __syncthreads();

#pragma unroll 1
  for (int i = 1; i <= 30; ++i) {
    const int Sc = 31 - i;
    const int buf = i & 1;
    const int last = (i == 30);
    const float* stOld = g_state[buf] + b * 8192;
    float* stNew = g_state[buf ^ 1] + b * 8192;
    const float* nhSrc = g_nh[buf] + (size_t)b * kP0 * 256;
    float* nhDst = g_nh[buf ^ 1] + (size_t)b * kP0 * 256;
    const float done = imask[n32 + i + 1];
    const int slot0 = sh_slot0, slot1 = sh_slot1;

    // ---- phase A: in-kernel g1 + g2 + cell for fresh slots (bit-exact chains) ----
    if (slot0 >= 0 || slot1 >= 0) {
      {
        int j0 = slot0 >= 0 ? slot0 : 0;
        int j1 = slot1 >= 0 ? slot1 : 0;
        if (tid < 512) As2[0][tid] = stOld[j0 * 256 + tid];
        else As2[1][tid - 512] = stOld[j1 * 256 + (tid - 512)];
      }
      __syncthreads();
      // g1 partials: Ks chunks of 128 (matches prior g_p1 order)
      {
        const int Ks = tid >> 8, c4 = tid & 255;
        float a00=0.f,a01=0.f,a02=0.f,a03=0.f,a10=0.f,a11=0.f,a12=0.f,a13=0.f;
        const float* wp = w1 + (size_t)(Ks * 128) * 1024 + c4 * 4;
        const float* A0 = &As2[0][Ks * 128];
        const float* A1 = &As2[1][Ks * 128];
#pragma unroll 4
        for (int kk = 0; kk < 128; ++kk) {
          float4 w = *(const float4*)(wp + (size_t)kk * 1024);
          float av0 = A0[kk], av1 = A1[kk];
          a00 = fmaf(av0, w.x, a00); a01 = fmaf(av0, w.y, a01);
          a02 = fmaf(av0, w.z, a02); a03 = fmaf(av0, w.w, a03);
          a10 = fmaf(av1, w.x, a10); a11 = fmaf(av1, w.y, a11);
          a12 = fmaf(av1, w.z, a12); a13 = fmaf(av1, w.w, a13);
        }
        float4 o0 = {a00, a01, a02, a03};
        float4 o1 = {a10, a11, a12, a13};
        *(float4*)&S[Ks][0][c4 * 4] = o0;
        *(float4*)&S[Ks][1][c4 * 4] = o1;
      }
      __syncthreads();
#pragma unroll
      for (int e = tid; e < 2048; e += 1024) {
        int s = e >> 10, col = e & 1023;
        IC[s][col] = geluf((((S[0][s][col] + S[1][s][col]) + S[2][s][col]) + S[3][s][col]) + b1[col]);
      }
      __syncthreads();
      // g2 partials: Ks chunks of 256 (matches prior g_p2 order)
      {
        const int Ks = tid >> 8, c4 = tid & 255;
        float a00=0.f,a01=0.f,a02=0.f,a03=0.f,a10=0.f,a11=0.f,a12=0.f,a13=0.f;
        const float* wp = w2 + (size_t)(Ks * 256) * 1024 + c4 * 4;
        const float* I0 = &IC[0][Ks * 256];
        const float* I1 = &IC[1][Ks * 256];
#pragma unroll 4
        for (int kk = 0; kk < 256; ++kk) {
          float4 w = *(const float4*)(wp + (size_t)kk * 1024);
          float iv0 = I0[kk], iv1 = I1[kk];
          a00 = fmaf(iv0, w.x, a00); a01 = fmaf(iv0, w.y, a01);
          a02 = fmaf(iv0, w.z, a02); a03 = fmaf(iv0, w.w, a03);
          a10 = fmaf(iv1, w.x, a10); a11 = fmaf(iv1, w.y, a11);
          a12 = fmaf(iv1, w.z, a12); a13 = fmaf(iv1, w.w, a13);
        }
        float4 o0 = {a00, a01, a02, a03};
        float4 o1 = {a10, a11, a12, a13};
        __syncthreads();   // all reads of IC (inter) complete before overwrite
        *(float4*)&S[0][0][0 * 4] = *(float4*)&S[0][0][0 * 4];  // no-op keep layout
        *(float4*)&IC[0][0] = *(float4*)&IC[0][0];              // (benign)
        // store partials back into S
        {
          float4 t0 = o0, t1 = o1;
          *(float4*)&S[Ks][0][c4 * 4] = t0;
          *(float4*)&S[Ks][1][c4 * 4] = t1;
        }
      }
      __syncthreads();
      // combine -> IC reused as cont
#pragma unroll
      for (int e = tid; e < 2048; e += 1024) {
        int s = e >> 10, col = e & 1023;
        IC[s][col] = (((S[0][s][col] + S[1][s][col]) + S[2][s][col]) + S[3][s][col]);
      }
      __syncthreads();
      // cell per valid srow (block-uniform loop)
#pragma unroll 1
      for (int s = 0; s < 2; ++s) {
        int j = (s == 0) ? slot0 : slot1;
        if (j < 0) continue;
        const int d = tid & 255;
        const bool act = tid < 256;
        float pre = 0.f;
        if (act) {
          float c0 = IC[s][d] + b2[d];
          float c1 = IC[s][256 + d] + b2[256 + d];
          float c2 = IC[s][512 + d] + b2[512 + d];
          float c3 = IC[s][768 + d] + b2[768 + d];
          float l = stOld[j * 256 + d];
          float r = stOld[(j + 1) * 256 + d];
          float f1 = 1.0f / (1.0f + expf(-c0));
          float f2 = 1.0f / (1.0f + expf(-c1));
          float ig = 1.0f / (1.0f + expf(-c2));
          pre = f1 * l + f2 * r + ig * c3;
        }
        float mean = bs16(pre, red16, tid) * (1.0f / 256.0f);
        float cen = pre - mean;
        float var = bs16(cen * cen, red16, tid) * (1.0f / 256.0f);
        float nh = cen / sqrtf(var + 1e-5f) * ln2g[d] + ln2b[d];
        if (act) sh_nhf[s][d] = nh;
        float mv = imask[n32 + i + 1 + j];
        float nhm = nh * mv;
        float pv[5];
#pragma unroll
        for (int t = 0; t < 5; ++t) pv[t] = nhm * decW[t * 256 + d];
#pragma unroll
        for (int t = 0; t < 5; ++t) {
          float v = pv[t];
#pragma unroll
          for (int o = 32; o > 0; o >>= 1) v += __shfl_down(v, o, 64);
          pv[t] = v;
        }
        __syncthreads();
        if (lane == 0 && wv < 4) {
#pragma unroll
          for (int t = 0; t < 5; ++t) w5s[wv][t] = pv[t];
        }
        __syncthreads();
        if (tid < 5) sh_s5f[s][tid] = w5s[0][tid] + w5s[1][tid] + w5s[2][tid] + w5s[3][tid];
        __syncthreads();
      }
    }
    __syncthreads();

    // ---- phase B: decide (wave 0) ----
    if (!last && tid < 64) {
      int j = lane;
      bool act = j < Sc;
      float mv = 0.f, lg = 0.f;
      if (act) {
        mv = imask[n32 + i + 1 + j];
        float t5 = decb[0];
        if (j >= 2) {
          int rw = j - 2;
          t5 += (rw == slot0) ? sh_s5f[0][0] : (rw == slot1) ? sh_s5f[1][0] : s5buf[buf][rw][0];
        }
        if (j >= 1) {
          int rw = j - 1;
          t5 += (rw == slot0) ? sh_s5f[0][1] : (rw == slot1) ? sh_s5f[1][1] : s5buf[buf][rw][1];
        }
        {
          int rw = j;
          t5 += (rw == slot0) ? sh_s5f[0][2] : (rw == slot1) ? sh_s5f[1][2] : s5buf[buf][rw][2];
        }
        if (j + 1 < Sc) {
          int rw = j + 1;
          t5 += (rw == slot0) ? sh_s5f[0][3] : (rw == slot1) ? sh_s5f[1][3] : s5buf[buf][rw][3];
        }
        if (j + 2 < Sc) {
          int rw = j + 2;
          t5 += (rw == slot0) ? sh_s5f[0][4] : (rw == slot1) ? sh_s5f[1][4] : s5buf[buf][rw][4];
        }
        lg = t5 / 35.77708763999664f;
      }
      uint32_t fk0, fk1, o0, o1;
      tf2x32(0u, 1234u, 0u, (uint32_t)i, fk0, fk1);
      uint32_t idx = (uint32_t)(b * Sc + j);
      tf2x32(fk0, fk1, 0u, idx, o0, o1);
      uint32_t bits = o0 ^ o1;
      float u = __uint_as_float((bits >> 9) | 0x3f800000u) - 1.0f;
      float gum = -logf(-logf(u + 1e-20f) + 1e-20f);
      float z = lg + gum;
      float zm = waveMax64(act ? z : -3.0e38f);
      float e = act ? expf(z - zm) : 0.f;
      float p = e / waveSum64(e);
      float y = act ? (p * mv + 1e-20f) : 0.f;
      float ys = y / waveSum64(y);
      float av = act ? ys : -1.f;
      int ai = j;
#pragma unroll
      for (int o = 32; o > 0; o >>= 1) {
        float ov = __shfl_xor(av, o, 64);
        int oi = __shfl_xor(ai, o, 64);
        if (ov > av || (ov == av && oi < ai)) { av = ov; ai = oi; }
      }
      float lm = waveMax64(act ? lg : -3.0e38f);
      float e2 = act ? expf(lg - lm) : 0.f;
      float p2 = e2 / waveSum64(e2);
      float y2 = act ? (p2 * mv + 1e-20f) : 0.f;
      float ps = y2 / waveSum64(y2);
      float ysk = __shfl(ys, ai, 64);
      float psk = __shfl(ps, ai, 64);
      float sv = (1.0f - ysk) + ysk;
      if (j == 0) {
        sh_k = ai;
        sh_sv = sv;
        sh_accu += done * logf(sv * psk + 1e-20f);
        int s0 = -1, s1 = -1;
        if (done != 0.0f) {
          if (ai >= 1) s0 = ai - 1;
          if (ai <= Sc - 2) s1 = ai;
        }
        sh_slot0 = s0;
        sh_slot1 = s1;
      }
    }
    __syncthreads();

    if (last) {
      if (wv == 0) {
        float4 ol = *(const float4*)&stOld[lane * 4];
        float4 nh4;
        if (slot0 == 0) nh4 = *(const float4*)&sh_nhf[0][lane * 4];
        else if (slot1 == 0) nh4 = *(const float4*)&sh_nhf[1][lane * 4];
        else nh4 = *(const float4*)&nhSrc[lane * 4];
        float4 o4;
        o4.x = done * nh4.x + (1.0f - done) * ol.x;
        o4.y = done * nh4.y + (1.0f - done) * ol.y;
        o4.z = done * nh4.z + (1.0f - done) * ol.z;
        o4.w = done * nh4.w + (1.0f - done) * ol.w;
        *(float4*)&stNew[lane * 4] = o4;
      }
    } else {
      // ---- phase C: merge + shift, 16 waves x 2 rows ----
      int k = sh_k;
      float sv = sh_sv;
#pragma unroll 1
      for (int rr = 0; rr < 2; ++rr) {
        int jrow = wv + 16 * rr;
        if (jrow >= Sc) continue;
        float4 ol = *(const float4*)&stOld[jrow * 256 + lane * 4];
        float4 ov4;
        if (done != 0.0f) {
          float4 mg;
          if (jrow < k) {
            mg = ol;
          } else if (jrow == k) {
            float4 nh4 = (k == slot0) ? *(const float4*)&sh_nhf[0][lane * 4]
                       : (k == slot1) ? *(const float4*)&sh_nhf[1][lane * 4]
                       : *(const float4*)&nhSrc[k * 256 + lane * 4];
            mg.x = sv * nh4.x + (1.0f - sv) * ol.x;
            mg.y = sv * nh4.y + (1.0f - sv) * ol.y;
            mg.z = sv * nh4.z + (1.0f - sv) * ol.z;
            mg.w = sv * nh4.w + (1.0f - sv) * ol.w;
          } else {
            float4 orr = *(const float4*)&stOld[(jrow + 1) * 256 + lane * 4];
            mg.x = (1.0f - sv) * ol.x + sv * orr.x;
            mg.y = (1.0f - sv) * ol.y + sv * orr.y;
            mg.z = (1.0f - sv) * ol.z + sv * orr.z;
            mg.w = (1.0f - sv) * ol.w + sv * orr.w;
          }
          ov4.x = done * mg.x + (1.0f - done) * ol.x;
          ov4.y = done * mg.y + (1.0f - done) * ol.y;
          ov4.z = done * mg.z + (1.0f - done) * ol.z;
          ov4.w = done * mg.w + (1.0f - done) * ol.w;
        } else {
          ov4 = ol;
        }
        *(float4*)&stNew[jrow * 256 + lane * 4] = ov4;
        if (jrow < Sc - 1) {
          int src = (done != 0.0f && jrow > k) ? jrow + 1 : jrow;
          float4 nv = (src == slot0) ? *(const float4*)&sh_nhf[0][lane * 4]
                    : (src == slot1) ? *(const float4*)&sh_nhf[1][lane * 4]
                    : *(const float4*)&nhSrc[src * 256 + lane * 4];
          *(float4*)&nhDst[jrow * 256 + lane * 4] = nv;
          float mv2 = imask[n32 + i + 2 + jrow];
          float pv[5];
#pragma unroll
          for (int t = 0; t < 5; ++t) {
            const float* dw = decW + t * 256 + lane * 4;
            pv[t] = (nv.x * dw[0] + nv.y * dw[1] + nv.z * dw[2] + nv.w * dw[3]) * mv2;
          }
#pragma unroll
          for (int t = 0; t < 5; ++t) {
            float v = pv[t];
#pragma unroll
            for (int o = 32; o > 0; o >>= 1) v += __shfl_down(v, o, 64);
            pv[t] = v;
          }
          if (lane == 0) {
#pragma unroll
            for (int t = 0; t < 5; ++t) s5buf[buf ^ 1][jrow][t] = pv[t];
          }
        }
      }
      __syncthreads();
    }
  }
  if (tid == 0) g_accu[b] = sh_accu;
}

// ---------------- final weighted sum over B ----------------
__global__ __launch_bounds__(256) void k_final(float* __restrict__ out) {
  int n = blockIdx.x, d = threadIdx.x;
  float a0 = g_accu[n * 4 + 0], a1 = g_accu[n * 4 + 1];
  float a2 = g_accu[n * 4 + 2], a3 = g_accu[n * 4 + 3];
  float mx = fmaxf(fmaxf(a0, a1), fmaxf(a2, a3));
  float e0 = expf(a0 - mx), e1 = expf(a1 - mx), e2 = expf(a2 - mx), e3 = expf(a3 - mx);
  float ssum = e0 + e1 + e2 + e3;
  const float* st1 = g_state[1];
  float h0 = st1[(n * 4 + 0) * 8192 + d];
  float h1 = st1[(n * 4 + 1) * 8192 + d];
  float h2 = st1[(n * 4 + 2) * 8192 + d];
  float h3 = st1[(n * 4 + 3) * 8192 + d];
  out[n * 256 + d] = (e0 / ssum) * h0 + (e1 / ssum) * h1 + (e2 / ssum) * h2 + (e3 / ssum) * h3;
}

extern "C" void kernel_launch(void* const* d_in, const int* in_sizes, int n_in,
                              void* d_out, int out_size, void* d_ws, size_t ws_size,
                              hipStream_t stream) {
  (void)in_sizes; (void)n_in; (void)d_ws; (void)ws_size; (void)out_size;
  const float* x = (const float*)d_in[0];
  const float* imask = (const float*)d_in[1];
  const float* wW = (const float*)d_in[2];
  const float* wb = (const float*)d_in[3];
  const float* lng = (const float*)d_in[4];
  const float* lnb = (const float*)d_in[5];
  const float* w1 = (const float*)d_in[6];
  const float* b1 = (const float*)d_in[7];
  const float* w2 = (const float*)d_in[8];
  const float* b2 = (const float*)d_in[9];
  const float* ln2g = (const float*)d_in[10];
  const float* ln2b = (const float*)d_in[11];
  const float* decW = (const float*)d_in[12];
  const float* decb = (const float*)d_in[13];
  float* out = (float*)d_out;

  k_embed<<<dim3(512), dim3(256), 0, stream>>>(x, wW, wb, lng, lnb);
  k_g1s<<<dim3(8, 31), dim3(128), 0, stream>>>(w1, b1);
  k_g2s<<<dim3(8, 31), dim3(128), 0, stream>>>(w2);
  k_cellfull<<<dim3(kM0), dim3(256), 0, stream>>>(imask, ln2g, ln2b, decW, b2);
  k_cm0<<<dim3(64, 8), dim3(256), 0, stream>>>(imask, decW, decb, ln2g, ln2b);
  k_tail<<<dim3(64), dim3(1024), 0, stream>>>(imask, decW, decb, b1, b2, ln2g,
                                              ln2b, w1, w2);
  k_final<<<dim3(16), dim3(256), 0, stream>>>(out);
}

// Round 12
// 1239.481 us; speedup vs baseline: 1.6221x; 1.6221x over previous
//
#include <hip/hip_runtime.h>
#include <cstdint>
#include <cstddef>

namespace {
constexpr int kP0 = 31;
constexpr int kM0 = 496;   // 16 n-seqs * 31 pairs at step 0
}

// ---------------- device state ----------------
__device__ float g_state[2][64 * 32 * 256];     // ping-pong per-b state
__device__ float g_nh[2][64 * kP0 * 256];       // pair-row cell outputs (b-indexed)
__device__ float g_s5[2][64 * kP0 * 5];
__device__ float g_nh0[kM0 * 256];              // step-0 n-indexed
__device__ float g_s50[kM0 * 5];
__device__ float g_inter0[(size_t)kM0 * 1024];
__device__ float g_cont0[(size_t)kM0 * 1024];
__device__ float g_p1[4][128 * 1024];           // tail g1 split-K partials
__device__ float g_p2[4][128 * 1024];           // tail g2 split-K partials
__device__ float g_accu[64];
__device__ int g_slots[2][128];                 // parity-buffered fresh-row indices

// ---------------- threefry2x32 (bit-exact jax, verified passing) ----------------
__device__ __forceinline__ void tf2x32(uint32_t k0, uint32_t k1, uint32_t x0,
                                       uint32_t x1, uint32_t& o0, uint32_t& o1) {
  uint32_t ks2 = k0 ^ k1 ^ 0x1BD11BDAu;
  x0 += k0; x1 += k1;
#define TF_ROT(v, r) (((v) << (r)) | ((v) >> (32 - (r))))
#define TF_RD(r) { x0 += x1; x1 = TF_ROT(x1, r); x1 ^= x0; }
  TF_RD(13) TF_RD(15) TF_RD(26) TF_RD(6)   x0 += k1;  x1 += ks2 + 1u;
  TF_RD(17) TF_RD(29) TF_RD(16) TF_RD(24)  x0 += ks2; x1 += k0 + 2u;
  TF_RD(13) TF_RD(15) TF_RD(26) TF_RD(6)   x0 += k0;  x1 += k1 + 3u;
  TF_RD(17) TF_RD(29) TF_RD(16) TF_RD(24)  x0 += k1;  x1 += ks2 + 4u;
  TF_RD(13) TF_RD(15) TF_RD(26) TF_RD(6)   x0 += ks2; x1 += k0 + 5u;
  o0 = x0; o1 = x1;
#undef TF_RD
#undef TF_ROT
}

__device__ __forceinline__ float blockSum256(float v, float* red4, int tid) {
#pragma unroll
  for (int o = 32; o > 0; o >>= 1) v += __shfl_down(v, o, 64);
  __syncthreads();
  if ((tid & 63) == 0) red4[tid >> 6] = v;
  __syncthreads();
  return red4[0] + red4[1] + red4[2] + red4[3];
}
__device__ __forceinline__ float waveMax64(float v) {
#pragma unroll
  for (int o = 32; o > 0; o >>= 1) v = fmaxf(v, __shfl_xor(v, o, 64));
  return v;
}
__device__ __forceinline__ float waveSum64(float v) {
#pragma unroll
  for (int o = 32; o > 0; o >>= 1) v += __shfl_xor(v, o, 64);
  return v;
}
__device__ __forceinline__ float geluf(float v) {
  return 0.5f * v * (1.0f + erff(v * 0.70710678118654752440f));
}

// ---------------- embed + LN, replicate to B copies ----------------
__global__ __launch_bounds__(256) void k_embed(const float* __restrict__ x,
                                               const float* __restrict__ wW,
                                               const float* __restrict__ wb,
                                               const float* __restrict__ lng,
                                               const float* __restrict__ lnb) {
  int row = blockIdx.x;  // n*32 + s
  int d = threadIdx.x;
  __shared__ float xs[256];
  __shared__ float red4[4];
  xs[d] = x[row * 256 + d];
  __syncthreads();
  float acc = wb[d];
  for (int k = 0; k < 256; ++k) acc = fmaf(xs[k], wW[k * 256 + d], acc);
  float mean = blockSum256(acc, red4, d) * (1.0f / 256.0f);
  float cen = acc - mean;
  float var = blockSum256(cen * cen, red4, d) * (1.0f / 256.0f);
  float o = cen / sqrtf(var + 1e-5f) * lng[d] + lnb[d];
  int n = row >> 5, s = row & 31;
#pragma unroll
  for (int bb = 0; bb < 4; ++bb)
    g_state[0][((n * 4 + bb) * 32 + s) * 256 + d] = o;
  if (row == 0 && d < 64) g_accu[d] = 0.0f;
}

// =============== step-0 GEMMs (r8 config: 128 thr, 4x4/thread, measured 45us) ===============

__global__ __launch_bounds__(128) void k_g1s(const float* __restrict__ w1,
                                             const float* __restrict__ b1) {
  __shared__ float As[64][20];
  __shared__ float Ws[64][132];
  const int tid = threadIdx.x;
  const int colB = blockIdx.x * 128;
  const int rowB = blockIdx.y * 16;
  const int rg = tid >> 5, cgp = tid & 31;
  const int ar = tid & 15, kq = tid >> 4;
  const int wc = tid & 31, wk = tid >> 5;
  const float* Ab;
  {
    int m = rowB + ar;
    int n = m / 31, j = m - n * 31;
    Ab = g_state[0] + (n * 4) * 8192 + j * 256;
  }
  float acc[4][4] = {};
  for (int c = 0; c < 8; ++c) {
    const int kb = c * 64;
#pragma unroll
    for (int q = 0; q < 2; ++q) {
      int kp = kq * 8 + q * 4;
      float4 a = *(const float4*)&Ab[kb + kp];
      As[kp + 0][ar] = a.x; As[kp + 1][ar] = a.y;
      As[kp + 2][ar] = a.z; As[kp + 3][ar] = a.w;
    }
#pragma unroll
    for (int q = 0; q < 16; ++q) {
      int kk = wk * 16 + q;
      *(float4*)&Ws[kk][wc * 4] =
          *(const float4*)&w1[(size_t)(kb + kk) * 1024 + colB + wc * 4];
    }
    __syncthreads();
#pragma unroll
    for (int kk = 0; kk < 64; ++kk) {
      float4 a4 = *(const float4*)&As[kk][rg * 4];
      float4 w4 = *(const float4*)&Ws[kk][cgp * 4];
      float av[4] = {a4.x, a4.y, a4.z, a4.w};
      float wv[4] = {w4.x, w4.y, w4.z, w4.w};
#pragma unroll
      for (int ri = 0; ri < 4; ++ri)
#pragma unroll
        for (int ci = 0; ci < 4; ++ci)
          acc[ri][ci] = fmaf(av[ri], wv[ci], acc[ri][ci]);
    }
    __syncthreads();
  }
  const int col = colB + cgp * 4;
  float4 bb = *(const float4*)&b1[col];
#pragma unroll
  for (int ri = 0; ri < 4; ++ri) {
    int m = rowB + rg * 4 + ri;
    float4 o;
    o.x = geluf(acc[ri][0] + bb.x); o.y = geluf(acc[ri][1] + bb.y);
    o.z = geluf(acc[ri][2] + bb.z); o.w = geluf(acc[ri][3] + bb.w);
    *(float4*)&g_inter0[(size_t)m * 1024 + col] = o;
  }
}

__global__ __launch_bounds__(128) void k_g2s(const float* __restrict__ w2) {
  __shared__ float As[64][20];
  __shared__ float Ws[64][132];
  const int tid = threadIdx.x;
  const int colB = blockIdx.x * 128;
  const int rowB = blockIdx.y * 16;
  const int rg = tid >> 5, cgp = tid & 31;
  const int ar = tid & 15, kq = tid >> 4;
  const int wc = tid & 31, wk = tid >> 5;
  const float* Ab = g_inter0 + (size_t)(rowB + ar) * 1024;
  float acc[4][4] = {};
  for (int c = 0; c < 16; ++c) {
    const int kb = c * 64;
#pragma unroll
    for (int q = 0; q < 2; ++q) {
      int kp = kq * 8 + q * 4;
      float4 a = *(const float4*)&Ab[kb + kp];
      As[kp + 0][ar] = a.x; As[kp + 1][ar] = a.y;
      As[kp + 2][ar] = a.z; As[kp + 3][ar] = a.w;
    }
#pragma unroll
    for (int q = 0; q < 16; ++q) {
      int kk = wk * 16 + q;
      *(float4*)&Ws[kk][wc * 4] =
          *(const float4*)&w2[(size_t)(kb + kk) * 1024 + colB + wc * 4];
    }
    __syncthreads();
#pragma unroll
    for (int kk = 0; kk < 64; ++kk) {
      float4 a4 = *(const float4*)&As[kk][rg * 4];
      float4 w4 = *(const float4*)&Ws[kk][cgp * 4];
      float av[4] = {a4.x, a4.y, a4.z, a4.w};
      float wv[4] = {w4.x, w4.y, w4.z, w4.w};
#pragma unroll
      for (int ri = 0; ri < 4; ++ri)
#pragma unroll
        for (int ci = 0; ci < 4; ++ci)
          acc[ri][ci] = fmaf(av[ri], wv[ci], acc[ri][ci]);
    }
    __syncthreads();
  }
  const int col = colB + cgp * 4;
#pragma unroll
  for (int ri = 0; ri < 4; ++ri) {
    int m = rowB + rg * 4 + ri;
    float4 o = {acc[ri][0], acc[ri][1], acc[ri][2], acc[ri][3]};
    *(float4*)&g_cont0[(size_t)m * 1024 + col] = o;
  }
}

// tail g2: partials over K-range [Ks*256, +256); A assembled as gelu(sum(p1)+b1)
__device__ __forceinline__ float4 g2t_loadA(int grow, int kpos, const float* __restrict__ b1) {
  size_t g = (size_t)grow * 1024 + kpos;
  float4 p0 = *(const float4*)&g_p1[0][g];
  float4 p1 = *(const float4*)&g_p1[1][g];
  float4 p2 = *(const float4*)&g_p1[2][g];
  float4 p3 = *(const float4*)&g_p1[3][g];
  float4 bb = *(const float4*)&b1[kpos];
  float4 r;
  r.x = geluf(p0.x + p1.x + p2.x + p3.x + bb.x);
  r.y = geluf(p0.y + p1.y + p2.y + p3.y + bb.y);
  r.z = geluf(p0.z + p1.z + p2.z + p3.z + bb.z);
  r.w = geluf(p0.w + p1.w + p2.w + p3.w + bb.w);
  return r;
}

// r6 tail g2: 256 thr, 16-row x 64-col tile, grid (16, 8, 4)
__global__ __launch_bounds__(256) void k_g2t(const float* __restrict__ w2,
                                             const float* __restrict__ b1) {
  __shared__ float As[64][17];
  __shared__ float Ws[64][68];
  const int tid = threadIdx.x;
  const int colB = blockIdx.x * 64;
  const int rowB = blockIdx.y * 16;
  const int Ks = blockIdx.z;
  const int kb0 = Ks * 256;
  const int row = tid >> 4, cg = tid & 15;
  const int ar = tid >> 4, ak = (tid & 15) * 4;
  const int grow = rowB + ar;
  float4 aR = g2t_loadA(grow, kb0 + ak, b1);
  float4 wR[4];
#pragma unroll
  for (int q = 0; q < 4; ++q) {
    int f = tid + q * 256; int kk = f >> 4, c4 = f & 15;
    wR[q] = *(const float4*)&w2[(size_t)(kb0 + kk) * 1024 + colB + c4 * 4];
  }
  float acc[4] = {};
  for (int c = 0; c < 4; ++c) {
    As[ak + 0][ar] = aR.x; As[ak + 1][ar] = aR.y;
    As[ak + 2][ar] = aR.z; As[ak + 3][ar] = aR.w;
#pragma unroll
    for (int q = 0; q < 4; ++q) {
      int f = tid + q * 256; int kk = f >> 4, c4 = f & 15;
      *(float4*)&Ws[kk][c4 * 4] = wR[q];
    }
    __syncthreads();
    if (c < 3) {
      int kb = kb0 + (c + 1) * 64;
      aR = g2t_loadA(grow, kb + ak, b1);
#pragma unroll
      for (int q = 0; q < 4; ++q) {
        int f = tid + q * 256; int kk = f >> 4, c4 = f & 15;
        wR[q] = *(const float4*)&w2[(size_t)(kb + kk) * 1024 + colB + c4 * 4];
      }
    }
#pragma unroll
    for (int kk = 0; kk < 64; ++kk) {
      float a = As[kk][row];
      float4 w = *(const float4*)&Ws[kk][cg * 4];
      acc[0] = fmaf(a, w.x, acc[0]); acc[1] = fmaf(a, w.y, acc[1]);
      acc[2] = fmaf(a, w.z, acc[2]); acc[3] = fmaf(a, w.w, acc[3]);
    }
    __syncthreads();
  }
  int col = colB + cg * 4;
  float4 o = {acc[0], acc[1], acc[2], acc[3]};
  *(float4*)&g_p2[Ks][(rowB + row) * 1024 + col] = o;
}

// ---------------- step-0 cell (all 496 rows) ----------------
__global__ __launch_bounds__(256) void k_cellfull(const float* __restrict__ imask,
                                                  const float* __restrict__ ln2g,
                                                  const float* __restrict__ ln2b,
                                                  const float* __restrict__ decW,
                                                  const float* __restrict__ b2) {
  int m = blockIdx.x;    // n*31 + j
  int d = threadIdx.x;
  int n = m / 31, j = m - n * 31;
  const float* st = g_state[0] + (n * 4) * 8192;
  const float* crow = g_cont0 + (size_t)m * 1024;
  float c0 = crow[d] + b2[d];
  float c1 = crow[256 + d] + b2[256 + d];
  float c2 = crow[512 + d] + b2[512 + d];
  float c3 = crow[768 + d] + b2[768 + d];
  float l = st[j * 256 + d];
  float r = st[(j + 1) * 256 + d];
  float f1 = 1.0f / (1.0f + expf(-c0));
  float f2 = 1.0f / (1.0f + expf(-c1));
  float ig = 1.0f / (1.0f + expf(-c2));
  float pre = f1 * l + f2 * r + ig * c3;
  __shared__ float red4[4];
  __shared__ float w5[4][5];
  float mean = blockSum256(pre, red4, d) * (1.0f / 256.0f);
  float cen = pre - mean;
  float var = blockSum256(cen * cen, red4, d) * (1.0f / 256.0f);
  float nh = cen / sqrtf(var + 1e-5f) * ln2g[d] + ln2b[d];
  g_nh0[m * 256 + d] = nh;
  float mv = imask[n * 32 + 1 + j];
  float nhm = nh * mv;
  float pv[5];
#pragma unroll
  for (int t = 0; t < 5; ++t) pv[t] = nhm * decW[t * 256 + d];
#pragma unroll
  for (int t = 0; t < 5; ++t)
#pragma unroll
    for (int o = 32; o > 0; o >>= 1) pv[t] += __shfl_down(pv[t], o, 64);
  __syncthreads();
  if ((d & 63) == 0) {
#pragma unroll
    for (int t = 0; t < 5; ++t) w5[d >> 6][t] = pv[t];
  }
  __syncthreads();
  if (d < 5) g_s50[m * 5 + d] = w5[0][d] + w5[1][d] + w5[2][d] + w5[3][d];
}

// ---------------- fused cell(fresh) + decide + merge + next-step g1 partials ----------------
// r6 structure: grid (64, 8): Phase C: 1 row/wave (jrow = grp*4+wv).
// Phase D: my = grp>>2 selects output srow, Ks = grp&3 the K-split.
__global__ __launch_bounds__(256) void k_cm(
    const float* __restrict__ imask, const float* __restrict__ decW,
    const float* __restrict__ decb, const float* __restrict__ b2,
    const float* __restrict__ ln2g, const float* __restrict__ ln2b,
    const float* __restrict__ w1, int i, int last) {
  const int b = blockIdx.x, grp = blockIdx.y;
  const int tid = threadIdx.x, st = tid, lane = tid & 63, wv = tid >> 6;
  const int Sc = 31 - i;
  const int buf = i & 1;
  const int n32 = (b >> 2) * 32;
  __shared__ float sh_nhf[2][256];
  __shared__ float sh_s5f[2][5];
  __shared__ float sA[3][256];
  __shared__ float red4[4];
  __shared__ float w5s[4][5];
  __shared__ int sh_k;
  __shared__ float sh_sv;
  int slot0 = -1, slot1 = -1;
  if (i > 0) { slot0 = g_slots[buf][2 * b]; slot1 = g_slots[buf][2 * b + 1]; }
  const float* s5Src = (i == 0) ? (g_s50 + (b >> 2) * kP0 * 5) : (g_s5[buf] + b * kP0 * 5);
  const float* nhSrcG = (i == 0) ? (g_nh0 + (size_t)(b >> 2) * kP0 * 256)
                                 : (g_nh[buf] + (size_t)b * kP0 * 256);
  const float* stOld = g_state[buf] + b * 8192;
  float* stNew = g_state[(i + 1) & 1] + b * 8192;
  float* nhDst = g_nh[(i + 1) & 1] + (size_t)b * kP0 * 256;
  float* s5Dst = g_s5[(i + 1) & 1] + b * kP0 * 5;
  float done = imask[n32 + i + 1];

  // ---- phase A: fresh-row cell (redundant per WG of b; block-uniform branches) ----
  if (i > 0) {
#pragma unroll 1
    for (int s = 0; s < 2; ++s) {
      int j = (s == 0) ? slot0 : slot1;
      if (j < 0) continue;
      int sr = 2 * b + s;
      float c[4];
#pragma unroll
      for (int q = 0; q < 4; ++q) {
        int g = sr * 1024 + q * 256 + st;
        float v = ((g_p2[0][g] + g_p2[1][g]) + g_p2[2][g]) + g_p2[3][g];
        c[q] = v + b2[q * 256 + st];
      }
      float l = stOld[j * 256 + st];
      float r = stOld[(j + 1) * 256 + st];
      float f1 = 1.0f / (1.0f + expf(-c[0]));
      float f2 = 1.0f / (1.0f + expf(-c[1]));
      float ig = 1.0f / (1.0f + expf(-c[2]));
      float pre = f1 * l + f2 * r + ig * c[3];
      float mean = blockSum256(pre, red4, st) * (1.0f / 256.0f);
      float cen = pre - mean;
      float var = blockSum256(cen * cen, red4, st) * (1.0f / 256.0f);
      float nh = cen / sqrtf(var + 1e-5f) * ln2g[st] + ln2b[st];
      sh_nhf[s][st] = nh;
      float mv = imask[n32 + i + 1 + j];
      float nhm = nh * mv;
      float pv[5];
#pragma unroll
      for (int t = 0; t < 5; ++t) pv[t] = nhm * decW[t * 256 + st];
#pragma unroll
      for (int t = 0; t < 5; ++t) {
        float v = pv[t];
#pragma unroll
        for (int o = 32; o > 0; o >>= 1) v += __shfl_down(v, o, 64);
        pv[t] = v;
      }
      __syncthreads();
      if (lane == 0) {
#pragma unroll
        for (int t = 0; t < 5; ++t) w5s[wv][t] = pv[t];
      }
      __syncthreads();
      if (st < 5) sh_s5f[s][st] = w5s[0][st] + w5s[1][st] + w5s[2][st] + w5s[3][st];
    }
  }
  __syncthreads();

  // ---- phase B: decide (wave 0), bit-exact round-2 math ----
  if (!last && tid < 64) {
    int j = lane;
    bool act = j < Sc;
    float mv = 0.f, lg = 0.f;
    if (act) {
      mv = imask[n32 + i + 1 + j];
      float t5 = decb[0];
      if (j >= 2) {
        int rw = j - 2;
        t5 += (i > 0 && rw == slot0) ? sh_s5f[0][0] : (i > 0 && rw == slot1) ? sh_s5f[1][0] : s5Src[rw * 5 + 0];
      }
      if (j >= 1) {
        int rw = j - 1;
        t5 += (i > 0 && rw == slot0) ? sh_s5f[0][1] : (i > 0 && rw == slot1) ? sh_s5f[1][1] : s5Src[rw * 5 + 1];
      }
      {
        int rw = j;
        t5 += (i > 0 && rw == slot0) ? sh_s5f[0][2] : (i > 0 && rw == slot1) ? sh_s5f[1][2] : s5Src[rw * 5 + 2];
      }
      if (j + 1 < Sc) {
        int rw = j + 1;
        t5 += (i > 0 && rw == slot0) ? sh_s5f[0][3] : (i > 0 && rw == slot1) ? sh_s5f[1][3] : s5Src[rw * 5 + 3];
      }
      if (j + 2 < Sc) {
        int rw = j + 2;
        t5 += (i > 0 && rw == slot0) ? sh_s5f[0][4] : (i > 0 && rw == slot1) ? sh_s5f[1][4] : s5Src[rw * 5 + 4];
      }
      lg = t5 / 35.77708763999664f;
    }
    uint32_t fk0, fk1, o0, o1;
    tf2x32(0u, 1234u, 0u, (uint32_t)i, fk0, fk1);
    uint32_t idx = (uint32_t)(b * Sc + j);
    tf2x32(fk0, fk1, 0u, idx, o0, o1);
    uint32_t bits = o0 ^ o1;
    float u = __uint_as_float((bits >> 9) | 0x3f800000u) - 1.0f;
    float gum = -logf(-logf(u + 1e-20f) + 1e-20f);
    float z = lg + gum;
    float zm = waveMax64(act ? z : -3.0e38f);
    float e = act ? expf(z - zm) : 0.f;
    float p = e / waveSum64(e);
    float y = act ? (p * mv + 1e-20f) : 0.f;
    float ys = y / waveSum64(y);
    float av = act ? ys : -1.f;
    int ai = j;
#pragma unroll
    for (int o = 32; o > 0; o >>= 1) {
      float ov = __shfl_xor(av, o, 64);
      int oi = __shfl_xor(ai, o, 64);
      if (ov > av || (ov == av && oi < ai)) { av = ov; ai = oi; }
    }
    float lm = waveMax64(act ? lg : -3.0e38f);
    float e2 = act ? expf(lg - lm) : 0.f;
    float p2 = e2 / waveSum64(e2);
    float y2 = act ? (p2 * mv + 1e-20f) : 0.f;
    float ps = y2 / waveSum64(y2);
    float ysk = __shfl(ys, ai, 64);
    float psk = __shfl(ps, ai, 64);
    float sv = (1.0f - ysk) + ysk;
    if (j == 0) {
      sh_k = ai;
      sh_sv = sv;
      if (grp == 0) {
        g_accu[b] += done * logf(sv * psk + 1e-20f);
        int s0 = -1, s1 = -1;
        if (done != 0.0f) {
          if (ai >= 1) s0 = ai - 1;
          if (ai <= Sc - 2) s1 = ai;
        }
        g_slots[(i + 1) & 1][2 * b] = s0;
        g_slots[(i + 1) & 1][2 * b + 1] = s1;
      }
    }
  }
  __syncthreads();

  // ---- last step (i==30): no select, state -> single row ----
  if (last) {
    if (grp == 0 && wv == 0) {
      float4 ol = *(const float4*)&stOld[lane * 4];
      float4 nh4;
      if (slot0 == 0) nh4 = *(const float4*)&sh_nhf[0][lane * 4];
      else if (slot1 == 0) nh4 = *(const float4*)&sh_nhf[1][lane * 4];
      else nh4 = *(const float4*)&nhSrcG[lane * 4];
      float4 o4;
      o4.x = done * nh4.x + (1.0f - done) * ol.x;
      o4.y = done * nh4.y + (1.0f - done) * ol.y;
      o4.z = done * nh4.z + (1.0f - done) * ol.z;
      o4.w = done * nh4.w + (1.0f - done) * ol.w;
      *(float4*)&stNew[lane * 4] = o4;
    }
    return;
  }

  // ---- phase C: merge + shift (1 row per wave) ----
  int k = sh_k;
  float sv = sh_sv;
  {
    int jrow = grp * 4 + wv;
    if (jrow < Sc) {
      float4 ol = *(const float4*)&stOld[jrow * 256 + lane * 4];
      float4 ov4;
      if (done != 0.0f) {
        float4 mg;
        if (jrow < k) {
          mg = ol;
        } else if (jrow == k) {
          float4 nh4 = (i > 0 && k == slot0) ? *(const float4*)&sh_nhf[0][lane * 4]
                     : (i > 0 && k == slot1) ? *(const float4*)&sh_nhf[1][lane * 4]
                     : *(const float4*)&nhSrcG[k * 256 + lane * 4];
          mg.x = sv * nh4.x + (1.0f - sv) * ol.x;
          mg.y = sv * nh4.y + (1.0f - sv) * ol.y;
          mg.z = sv * nh4.z + (1.0f - sv) * ol.z;
          mg.w = sv * nh4.w + (1.0f - sv) * ol.w;
        } else {
          float4 orr = *(const float4*)&stOld[(jrow + 1) * 256 + lane * 4];
          mg.x = (1.0f - sv) * ol.x + sv * orr.x;
          mg.y = (1.0f - sv) * ol.y + sv * orr.y;
          mg.z = (1.0f - sv) * ol.z + sv * orr.z;
          mg.w = (1.0f - sv) * ol.w + sv * orr.w;
        }
        ov4.x = done * mg.x + (1.0f - done) * ol.x;
        ov4.y = done * mg.y + (1.0f - done) * ol.y;
        ov4.z = done * mg.z + (1.0f - done) * ol.z;
        ov4.w = done * mg.w + (1.0f - done) * ol.w;
      } else {
        ov4 = ol;
      }
      *(float4*)&stNew[jrow * 256 + lane * 4] = ov4;
      if (jrow < Sc - 1) {
        int src = (done != 0.0f && jrow > k) ? jrow + 1 : jrow;
        float4 nv = (i > 0 && src == slot0) ? *(const float4*)&sh_nhf[0][lane * 4]
                  : (i > 0 && src == slot1) ? *(const float4*)&sh_nhf[1][lane * 4]
                  : *(const float4*)&nhSrcG[src * 256 + lane * 4];
        *(float4*)&nhDst[jrow * 256 + lane * 4] = nv;
        float mv2 = imask[n32 + i + 2 + jrow];
        float pv[5];
#pragma unroll
        for (int t = 0; t < 5; ++t) {
          const float* dw = decW + t * 256 + lane * 4;
          pv[t] = (nv.x * dw[0] + nv.y * dw[1] + nv.z * dw[2] + nv.w * dw[3]) * mv2;
        }
#pragma unroll
        for (int t = 0; t < 5; ++t) {
          float v = pv[t];
#pragma unroll
          for (int o = 32; o > 0; o >>= 1) v += __shfl_down(v, o, 64);
          pv[t] = v;
        }
        if (lane == 0) {
#pragma unroll
          for (int t = 0; t < 5; ++t) s5Dst[jrow * 5 + t] = pv[t];
        }
      }
    }
  }

  // ---- phase D: next-step g1 split-K partial (my = grp>>2 srow, Ks = grp&3) ----
  if (done != 0.0f) {
    __syncthreads();
    {
      int d = st;
      float nhKv = (i > 0 && k == slot0) ? sh_nhf[0][d]
                 : (i > 0 && k == slot1) ? sh_nhf[1][d]
                 : nhSrcG[k * 256 + d];
#pragma unroll
      for (int t = 0; t < 3; ++t) {
        int r = k - 1 + t;
        if (r < 0 || r > Sc - 1) continue;
        float ol = stOld[r * 256 + d];
        float mg;
        if (r < k) mg = ol;
        else if (r == k) mg = sv * nhKv + (1.0f - sv) * ol;
        else mg = (1.0f - sv) * ol + sv * stOld[(r + 1) * 256 + d];
        sA[t][d] = done * mg + (1.0f - done) * ol;
      }
    }
    __syncthreads();
    const int my = grp >> 2;
    const int Ks = grp & 3;
    const int has = (my == 0) ? (k >= 1) : (k <= Sc - 2);
    const int kb0 = Ks * 128;
    const float* A = (my == 0) ? ((Ks < 2) ? sA[0] : sA[1])
                               : ((Ks < 2) ? sA[1] : sA[2]);
    const int koff = (Ks < 2) ? kb0 : (kb0 - 256);
    const int col = st * 4;
    float a0 = 0.f, a1 = 0.f, a2 = 0.f, a3 = 0.f;
    for (int kk = 0; kk < 128; ++kk) {
      float4 w = *(const float4*)&w1[(size_t)(kb0 + kk) * 1024 + col];
      float av = A[koff + kk];
      a0 = fmaf(av, w.x, a0); a1 = fmaf(av, w.y, a1);
      a2 = fmaf(av, w.z, a2); a3 = fmaf(av, w.w, a3);
    }
    if (has) {
      float4 o = {a0, a1, a2, a3};
      *(float4*)&g_p1[Ks][(2 * b + my) * 1024 + col] = o;
    }
  }
}

// ---------------- final weighted sum over B ----------------
__global__ __launch_bounds__(256) void k_final(float* __restrict__ out) {
  int n = blockIdx.x, d = threadIdx.x;
  float a0 = g_accu[n * 4 + 0], a1 = g_accu[n * 4 + 1];
  float a2 = g_accu[n * 4 + 2], a3 = g_accu[n * 4 + 3];
  float mx = fmaxf(fmaxf(a0, a1), fmaxf(a2, a3));
  float e0 = expf(a0 - mx), e1 = expf(a1 - mx), e2 = expf(a2 - mx), e3 = expf(a3 - mx);
  float ssum = e0 + e1 + e2 + e3;
  const float* st1 = g_state[1];
  float h0 = st1[(n * 4 + 0) * 8192 + d];
  float h1 = st1[(n * 4 + 1) * 8192 + d];
  float h2 = st1[(n * 4 + 2) * 8192 + d];
  float h3 = st1[(n * 4 + 3) * 8192 + d];
  out[n * 256 + d] = (e0 / ssum) * h0 + (e1 / ssum) * h1 + (e2 / ssum) * h2 + (e3 / ssum) * h3;
}

extern "C" void kernel_launch(void* const* d_in, const int* in_sizes, int n_in,
                              void* d_out, int out_size, void* d_ws, size_t ws_size,
                              hipStream_t stream) {
  (void)in_sizes; (void)n_in; (void)d_ws; (void)ws_size; (void)out_size;
  const float* x = (const float*)d_in[0];
  const float* imask = (const float*)d_in[1];
  const float* wW = (const float*)d_in[2];
  const float* wb = (const float*)d_in[3];
  const float* lng = (const float*)d_in[4];
  const float* lnb = (const float*)d_in[5];
  const float* w1 = (const float*)d_in[6];
  const float* b1 = (const float*)d_in[7];
  const float* w2 = (const float*)d_in[8];
  const float* b2 = (const float*)d_in[9];
  const float* ln2g = (const float*)d_in[10];
  const float* ln2b = (const float*)d_in[11];
  const float* decW = (const float*)d_in[12];
  const float* decb = (const float*)d_in[13];
  float* out = (float*)d_out;

  k_embed<<<dim3(512), dim3(256), 0, stream>>>(x, wW, wb, lng, lnb);
  k_g1s<<<dim3(8, 31), dim3(128), 0, stream>>>(w1, b1);
  k_g2s<<<dim3(8, 31), dim3(128), 0, stream>>>(w2);
  k_cellfull<<<dim3(kM0), dim3(256), 0, stream>>>(imask, ln2g, ln2b, decW, b2);
  k_cm<<<dim3(64, 8), dim3(256), 0, stream>>>(imask, decW, decb, b2, ln2g, ln2b, w1, 0, 0);
  for (int i = 1; i <= 30; ++i) {
    k_g2t<<<dim3(16, 8, 4), dim3(256), 0, stream>>>(w2, b1);
    int lastf = (i == 30) ? 1 : 0;
    k_cm<<<dim3(64, lastf ? 1 : 8), dim3(256), 0, stream>>>(imask, decW, decb, b2,
                                                            ln2g, ln2b, w1, i, lastf);
  }
  k_final<<<dim3(16), dim3(256), 0, stream>>>(out);
}